// Round 1
// 73.463 us; speedup vs baseline: 1.0910x; 1.0910x over previous
//
#include <hip/hip_runtime.h>

typedef float v2f __attribute__((ext_vector_type(2)));

#define HW 32
#define QD 8
#define ROWS 18              // 16 output rows + 2 halo
#define TW 34                // 32 cols + 2 halo
#define TILE (ROWS * TW)     // 612 floats per channel

__device__ __forceinline__ float sigmoidf(float v) {
    // 1/(1+exp(-v)) via v_exp_f32 + v_rcp_f32; absmax vs np ref 4.9e-4 in prior rounds.
    return __builtin_amdgcn_rcpf(1.0f + __expf(-v));
}

__device__ __forceinline__ v2f sig2(v2f v) {
    v2f r; r.x = sigmoidf(v.x); r.y = sigmoidf(v.y); return r;
}

// Packed 4-input multilinear LUT over 16 corners: component .x evaluates table Wa,
// component .y evaluates table Wb (two INDEPENDENT LUTs of the same pixel).
// Lowers to v_pk_fma_f32 / v_pk_add_f32; weight subs are wave-uniform scalars.
__device__ __forceinline__ v2f lut4p(const v2f* s, const float* __restrict__ Wa,
                                     const float* __restrict__ Wb) {
    v2f a[8];
#pragma unroll
    for (int j = 0; j < 8; ++j) {
        const v2f dv = {Wa[j + 8] - Wa[j], Wb[j + 8] - Wb[j]};
        const v2f wv = {Wa[j], Wb[j]};
        a[j] = __builtin_elementwise_fma(s[3], dv, wv);
    }
#pragma unroll
    for (int j = 0; j < 4; ++j) a[j] = __builtin_elementwise_fma(s[2], a[j + 4] - a[j], a[j]);
#pragma unroll
    for (int j = 0; j < 2; ++j) a[j] = __builtin_elementwise_fma(s[1], a[j + 2] - a[j], a[j]);
    return __builtin_elementwise_fma(s[0], a[1] - a[0], a[0]);
}

// Scalar variant for the odd tail LUTs.
__device__ __forceinline__ float lut4s(const float* s, const float* __restrict__ W) {
    float a[8];
#pragma unroll
    for (int j = 0; j < 8; ++j) a[j] = fmaf(s[3], W[j + 8] - W[j], W[j]);
#pragma unroll
    for (int j = 0; j < 4; ++j) a[j] = fmaf(s[2], a[j + 4] - a[j], a[j]);
#pragma unroll
    for (int j = 0; j < 2; ++j) a[j] = fmaf(s[1], a[j + 2] - a[j], a[j]);
    return fmaf(s[0], a[1] - a[0], a[0]);
}

// t[k] (k compile-time after unroll) from the packed level-0 outputs
#define TGET(k) (((k) & 1) ? t2[(k) >> 1].y : t2[(k) >> 1].x)

// One block per (o, b, row-half): 512 threads, 1 pixel each (16 rows x 32 cols).
// Grid 512 blocks -> 2 blocks/CU -> 16 waves/CU = 4 waves/SIMD (2x the prior
// occupancy). v_pk packing is preserved by pairing the 18 independent level-0
// LUTs of one pixel instead of pairing two pixels.
__global__ __launch_bounds__(512, 4) void lt_conv_kernel(
    const float* __restrict__ x,   // [8,64,32,32]
    const float* __restrict__ w0,  // [32,18,16]
    const float* __restrict__ w1,  // [32,5,16]
    const float* __restrict__ w2,  // [32,2,16]
    const float* __restrict__ w3,  // [32,1,16]
    const int*   __restrict__ ci,  // [32,8]
    float*       __restrict__ out) // [8,32,32,32]
{
    const int bi = blockIdx.x;
    const int o = bi & 31;
    const int b = (bi >> 5) & 7;
    const int h = bi >> 8;               // 0/1: which 16-row half

    __shared__ float stile[QD * TILE];   // 19,584 B
    __shared__ int   ldsci[QD];

    const int tid = threadIdx.x;
    if (tid < QD) ldsci[tid] = ci[o * QD + tid];
    __syncthreads();

    // ---- stage: sigmoid(x) for 8 channels, 18x34 (1-halo); OOB = sigmoid(0)=0.5
    const int y0 = h * 16 - 1;           // global row of local row 0
#pragma unroll
    for (int it = 0; it < 10; ++it) {
        const int idx = tid + it * 512;
        if (idx < QD * TILE) {
            const int q   = idx / TILE;
            const int rem = idx - q * TILE;
            const int row = rem / TW;
            const int col = rem - row * TW;
            const int y = y0 + row, xx = col - 1;
            float v = 0.0f;
            if ((unsigned)y < 32u && (unsigned)xx < 32u) {
                const int c = ldsci[q];
                v = x[(((size_t)b * 64 + c) * HW + y) * HW + xx];
            }
            stile[idx] = sigmoidf(v);
        }
    }
    __syncthreads();

    const int wo = tid & 31;             // output column
    const int r  = tid >> 5;             // local output row 0..15

    // ---- level 0: 18 LUTs over the 72 patch values (flat = q*9 + dy*3 + dx),
    // packed two-LUTs-per-v2f.
    const float* W0 = w0 + o * 18 * 16;
    v2f t2[9];
#pragma unroll
    for (int lp = 0; lp < 9; ++lp) {
        v2f s[4];
#pragma unroll
        for (int i = 0; i < 4; ++i) {
            {   // LUT 2*lp, input i
                const int flat = 8 * lp + i;
                const int q = flat / 9, k = flat - 9 * q;
                const int dy = k / 3, dx = k - 3 * dy;
                s[i].x = stile[q * TILE + (r + dy) * TW + (wo + dx)];
            }
            {   // LUT 2*lp+1, input i
                const int flat = 8 * lp + 4 + i;
                const int q = flat / 9, k = flat - 9 * q;
                const int dy = k / 3, dx = k - 3 * dy;
                s[i].y = stile[q * TILE + (r + dy) * TW + (wo + dx)];
            }
        }
        t2[lp] = sig2(lut4p(s, W0 + (2 * lp) * 16, W0 + (2 * lp + 1) * 16));
    }

    // ---- level 1: 5 LUTs (18 inputs padded to 20 with 0.5); pack (0,1) and (2,3)
    const float* W1 = w1 + o * 5 * 16;
    float u[5];
    {
        v2f s[4];
#pragma unroll
        for (int i = 0; i < 4; ++i) { s[i].x = TGET(i);     s[i].y = TGET(4 + i);  }
        const v2f r01 = sig2(lut4p(s, W1 + 0 * 16, W1 + 1 * 16));
        u[0] = r01.x; u[1] = r01.y;
    }
    {
        v2f s[4];
#pragma unroll
        for (int i = 0; i < 4; ++i) { s[i].x = TGET(8 + i); s[i].y = TGET(12 + i); }
        const v2f r23 = sig2(lut4p(s, W1 + 2 * 16, W1 + 3 * 16));
        u[2] = r23.x; u[3] = r23.y;
    }
    {
        const float s4[4] = {TGET(16), TGET(17), 0.5f, 0.5f};
        u[4] = sigmoidf(lut4s(s4, W1 + 4 * 16));
    }

    // ---- level 2: 2 LUTs (5 inputs padded to 8), packed into one v2f
    const float* W2 = w2 + o * 2 * 16;
    v2f s2v[4];
    s2v[0].x = u[0]; s2v[0].y = u[4];
    s2v[1].x = u[1]; s2v[1].y = 0.5f;
    s2v[2].x = u[2]; s2v[2].y = 0.5f;
    s2v[3].x = u[3]; s2v[3].y = 0.5f;
    const v2f vv = sig2(lut4p(s2v, W2, W2 + 16));

    // ---- level 3: final LUT (2 inputs padded to 4), no sigmoid
    const float* W3 = w3 + o * 16;
    const float s3[4] = {vv.x, vv.y, 0.5f, 0.5f};
    const float res = lut4s(s3, W3);

    out[(((size_t)b * 32 + o) * HW + (h * 16 + r)) * HW + wo] = res;
}

extern "C" void kernel_launch(void* const* d_in, const int* in_sizes, int n_in,
                              void* d_out, int out_size, void* d_ws, size_t ws_size,
                              hipStream_t stream) {
    const float* x  = (const float*)d_in[0];
    const float* w0 = (const float*)d_in[1];
    const float* w1 = (const float*)d_in[2];
    const float* w2 = (const float*)d_in[3];
    const float* w3 = (const float*)d_in[4];
    const int*   ci = (const int*)d_in[5];
    float* out = (float*)d_out;

    lt_conv_kernel<<<dim3(32 * 8 * 2), dim3(512), 0, stream>>>(x, w0, w1, w2, w3, ci, out);
}

// Round 3
// 72.944 us; speedup vs baseline: 1.0987x; 1.0071x over previous
//
#include <hip/hip_runtime.h>

typedef float v2f __attribute__((ext_vector_type(2)));
typedef float v4f __attribute__((ext_vector_type(4)));

#define HW 32
#define QD 8
#define ROWS 18              // 16 output rows + 2 halo
#define TW 34                // 32 cols + 2 halo
#define TILE (ROWS * TW)     // 612 floats per channel
#define NPAIR 14             // packed LUT pairs (see table in kernel)

__device__ __forceinline__ float sigmoidf(float v) {
    // 1/(1+exp(-v)) via v_exp_f32 + v_rcp_f32; absmax vs np ref 4.9e-4 in prior rounds.
    return __builtin_amdgcn_rcpf(1.0f + __expf(-v));
}

__device__ __forceinline__ v2f sig2(v2f v) {
    v2f r; r.x = sigmoidf(v.x); r.y = sigmoidf(v.y); return r;
}

// Packed 4-input multilinear LUT over 16 corners; component .x evaluates LUT a,
// .y evaluates LUT b. Weights come PRE-PAIRED from LDS: pw4[k] packs corners
// {2k,2k+1} of both LUTs, pd4[k] the matching (W[j+8]-W[j]) deltas. Each v4f
// load is one ds_read_b128 at a wave-uniform address (broadcast, conflict-free),
// and the v2f halves alias the v4f registers (no extraction movs). This removes
// all per-lane marshaling of block-uniform weights from the VALU pipe.
__device__ __forceinline__ v2f lut4p(const v2f* s, const v4f* pw4, const v4f* pd4) {
    v2f a[8];
#pragma unroll
    for (int k = 0; k < 4; ++k) {
        const v4f w = pw4[k], d = pd4[k];
        const v2f wlo = {w.x, w.y}, whi = {w.z, w.w};
        const v2f dlo = {d.x, d.y}, dhi = {d.z, d.w};
        a[2 * k]     = __builtin_elementwise_fma(s[3], dlo, wlo);
        a[2 * k + 1] = __builtin_elementwise_fma(s[3], dhi, whi);
    }
#pragma unroll
    for (int j = 0; j < 4; ++j) a[j] = __builtin_elementwise_fma(s[2], a[j + 4] - a[j], a[j]);
#pragma unroll
    for (int j = 0; j < 2; ++j) a[j] = __builtin_elementwise_fma(s[1], a[j + 2] - a[j], a[j]);
    return __builtin_elementwise_fma(s[0], a[1] - a[0], a[0]);
}

// t[k] (k compile-time after unroll) from the packed level-0 outputs
#define TGET(k) (((k) & 1) ? t2[(k) >> 1].y : t2[(k) >> 1].x)

// One block per (o, b, row-half): 512 threads, 1 pixel each (16 rows x 32 cols).
// Grid 512 -> 2 blocks/CU -> 4 waves/SIMD. All 26 LUTs are evaluated as 14
// packed pairs (dummy-duplicated tables for the 2 odd tails).
__global__ __launch_bounds__(512, 4) void lt_conv_kernel(
    const float* __restrict__ x,   // [8,64,32,32]
    const float* __restrict__ w0,  // [32,18,16]
    const float* __restrict__ w1,  // [32,5,16]
    const float* __restrict__ w2,  // [32,2,16]
    const float* __restrict__ w3,  // [32,1,16]
    const int*   __restrict__ ci,  // [32,8]
    float*       __restrict__ out) // [8,32,32,32]
{
    const int bi = blockIdx.x;
    const int o = bi & 31;
    const int b = (bi >> 5) & 7;
    const int h = bi >> 8;               // 0/1: which 16-row half

    __shared__ float stile[QD * TILE];                       // 19,584 B
    __shared__ v2f pwts[NPAIR][8] __attribute__((aligned(16)));  // 896 B
    __shared__ v2f pdts[NPAIR][8] __attribute__((aligned(16)));  // 896 B
    __shared__ int ldsci[QD];

    const int tid = threadIdx.x;
    if (tid < QD) ldsci[tid] = ci[o * QD + tid];

    // ---- stage packed weight-pair tables (block-uniform, built once).
    // pair p -> (LUT a, LUT b):
    //   0..8 : level0 LUTs (2p, 2p+1)
    //   9,10 : level1 LUTs (0,1), (2,3)
    //   11   : level1 LUT 4 (b = dup of a)
    //   12   : level2 LUTs (0,1)
    //   13   : level3 LUT   (b = dup of a)
    if (tid < NPAIR * 8) {
        const int p = tid >> 3, j = tid & 7;
        const float *A, *Bp;
        if (p < 9)        { A = w0 + o * 288 + (2 * p) * 16;       Bp = A + 16; }
        else if (p < 11)  { A = w1 + o * 80 + (2 * (p - 9)) * 16;  Bp = A + 16; }
        else if (p == 11) { A = w1 + o * 80 + 64;                  Bp = A;      }
        else if (p == 12) { A = w2 + o * 32;                       Bp = A + 16; }
        else              { A = w3 + o * 16;                       Bp = A;      }
        pwts[p][j] = (v2f){A[j], Bp[j]};
        pdts[p][j] = (v2f){A[j + 8] - A[j], Bp[j + 8] - Bp[j]};
    }
    __syncthreads();

    // ---- stage: sigmoid(x) for 8 channels, 18x34 (1-halo); OOB = sigmoid(0)=0.5
    const int y0 = h * 16 - 1;           // global row of local row 0
#pragma unroll
    for (int it = 0; it < 10; ++it) {
        const int idx = tid + it * 512;
        if (idx < QD * TILE) {
            const int q   = idx / TILE;
            const int rem = idx - q * TILE;
            const int row = rem / TW;
            const int col = rem - row * TW;
            const int y = y0 + row, xx = col - 1;
            float v = 0.0f;
            if ((unsigned)y < 32u && (unsigned)xx < 32u) {
                const int c = ldsci[q];
                v = x[(((size_t)b * 64 + c) * HW + y) * HW + xx];
            }
            stile[idx] = sigmoidf(v);
        }
    }
    __syncthreads();

    const int wo = tid & 31;             // output column
    const int r  = tid >> 5;             // local output row 0..15

#define PW(p) (reinterpret_cast<const v4f*>(&pwts[p][0]))
#define PD(p) (reinterpret_cast<const v4f*>(&pdts[p][0]))

    // ---- level 0: 18 LUTs over the 72 patch values (flat = q*9 + dy*3 + dx),
    // packed two-LUTs-per-v2f.
    v2f t2[9];
#pragma unroll
    for (int lp = 0; lp < 9; ++lp) {
        v2f s[4];
#pragma unroll
        for (int i = 0; i < 4; ++i) {
            {   // LUT 2*lp, input i
                const int flat = 8 * lp + i;
                const int q = flat / 9, k = flat - 9 * q;
                const int dy = k / 3, dx = k - 3 * dy;
                s[i].x = stile[q * TILE + (r + dy) * TW + (wo + dx)];
            }
            {   // LUT 2*lp+1, input i
                const int flat = 8 * lp + 4 + i;
                const int q = flat / 9, k = flat - 9 * q;
                const int dy = k / 3, dx = k - 3 * dy;
                s[i].y = stile[q * TILE + (r + dy) * TW + (wo + dx)];
            }
        }
        t2[lp] = sig2(lut4p(s, PW(lp), PD(lp)));
    }

    // ---- level 1: 5 LUTs (18 inputs padded to 20 with 0.5)
    const v2f h2 = {0.5f, 0.5f};
    float u[5];
    {
        v2f s[4];
#pragma unroll
        for (int i = 0; i < 4; ++i) { s[i].x = TGET(i);     s[i].y = TGET(4 + i);  }
        const v2f r01 = sig2(lut4p(s, PW(9), PD(9)));
        u[0] = r01.x; u[1] = r01.y;
    }
    {
        v2f s[4];
#pragma unroll
        for (int i = 0; i < 4; ++i) { s[i].x = TGET(8 + i); s[i].y = TGET(12 + i); }
        const v2f r23 = sig2(lut4p(s, PW(10), PD(10)));
        u[2] = r23.x; u[3] = r23.y;
    }
    {
        v2f s[4];
        s[0] = (v2f){TGET(16), TGET(16)};
        s[1] = (v2f){TGET(17), TGET(17)};
        s[2] = h2; s[3] = h2;
        u[4] = sigmoidf(lut4p(s, PW(11), PD(11)).x);
    }

    // ---- level 2: 2 LUTs (5 inputs padded to 8), packed into one v2f
    v2f s2v[4];
    s2v[0].x = u[0]; s2v[0].y = u[4];
    s2v[1].x = u[1]; s2v[1].y = 0.5f;
    s2v[2].x = u[2]; s2v[2].y = 0.5f;
    s2v[3].x = u[3]; s2v[3].y = 0.5f;
    const v2f vv = sig2(lut4p(s2v, PW(12), PD(12)));

    // ---- level 3: final LUT (2 inputs padded to 4), no sigmoid
    v2f s3v[4];
    s3v[0] = (v2f){vv.x, vv.x};
    s3v[1] = (v2f){vv.y, vv.y};
    s3v[2] = h2; s3v[3] = h2;
    const float res = lut4p(s3v, PW(13), PD(13)).x;

    out[(((size_t)b * 32 + o) * HW + (h * 16 + r)) * HW + wo] = res;
}

extern "C" void kernel_launch(void* const* d_in, const int* in_sizes, int n_in,
                              void* d_out, int out_size, void* d_ws, size_t ws_size,
                              hipStream_t stream) {
    const float* x  = (const float*)d_in[0];
    const float* w0 = (const float*)d_in[1];
    const float* w1 = (const float*)d_in[2];
    const float* w2 = (const float*)d_in[3];
    const float* w3 = (const float*)d_in[4];
    const int*   ci = (const int*)d_in[5];
    float* out = (float*)d_out;

    lt_conv_kernel<<<dim3(32 * 8 * 2), dim3(512), 0, stream>>>(x, w0, w1, w2, w3, ci, out);
}